// Round 1
// baseline (5975.887 us; speedup 1.0000x reference)
//
#include <hip/hip_runtime.h>
#include <math.h>

#define NN 50000
#define NE 800000
#define FD 128

// ---------------- degree / normalization ----------------

__global__ __launch_bounds__(256) void k_zero_int(int* __restrict__ p, int n) {
    int i = blockIdx.x * 256 + threadIdx.x;
    if (i < n) p[i] = 0;
}

__global__ __launch_bounds__(256) void k_count(const int* __restrict__ dst, int* __restrict__ deg) {
    int e = blockIdx.x * 256 + threadIdx.x;
    if (e < NE) atomicAdd(&deg[dst[e]], 1);
}

__global__ __launch_bounds__(256) void k_dis(const int* __restrict__ deg, float* __restrict__ dis) {
    int i = blockIdx.x * 256 + threadIdx.x;
    if (i < NN) dis[i] = (float)(1.0 / sqrt((double)(deg[i] + 1)));
}

// ---------------- node GEMM: C[nrows x 128] = A[nrows x 128] @ W[128 x 128] ----------------
// 32-row tile per block, 256 threads = (8 row-groups x 32 col-groups), 4x4 register block.

__global__ __launch_bounds__(256) void k_gemm(const float* __restrict__ A,
                                              const float* __restrict__ W,
                                              float* __restrict__ C, int nrows) {
    __shared__ float As[32][128];
    const int t = threadIdx.x;
    const int row0 = blockIdx.x * 32;

    for (int idx = t; idx < 32 * 32; idx += 256) {
        int r = idx >> 5, c = idx & 31;
        float4 v = make_float4(0.f, 0.f, 0.f, 0.f);
        if (row0 + r < nrows)
            v = reinterpret_cast<const float4*>(A)[(size_t)(row0 + r) * 32 + c];
        reinterpret_cast<float4*>(&As[r][0])[c] = v;
    }
    __syncthreads();

    const int cg = t & 31;   // col group: cols cg*4 .. cg*4+3
    const int eg = t >> 5;   // row group: rows eg*4 .. eg*4+3
    float acc[4][4] = {{0.f}};

    const float4* W4 = reinterpret_cast<const float4*>(W);
#pragma unroll 4
    for (int k = 0; k < 128; ++k) {
        float4 w = W4[k * 32 + cg];
        float a0 = As[eg * 4 + 0][k];
        float a1 = As[eg * 4 + 1][k];
        float a2 = As[eg * 4 + 2][k];
        float a3 = As[eg * 4 + 3][k];
        acc[0][0] += a0 * w.x; acc[0][1] += a0 * w.y; acc[0][2] += a0 * w.z; acc[0][3] += a0 * w.w;
        acc[1][0] += a1 * w.x; acc[1][1] += a1 * w.y; acc[1][2] += a1 * w.z; acc[1][3] += a1 * w.w;
        acc[2][0] += a2 * w.x; acc[2][1] += a2 * w.y; acc[2][2] += a2 * w.z; acc[2][3] += a2 * w.w;
        acc[3][0] += a3 * w.x; acc[3][1] += a3 * w.y; acc[3][2] += a3 * w.z; acc[3][3] += a3 * w.w;
    }

#pragma unroll
    for (int i = 0; i < 4; ++i) {
        int r = row0 + eg * 4 + i;
        if (r < nrows) {
            float4 o = make_float4(acc[i][0], acc[i][1], acc[i][2], acc[i][3]);
            reinterpret_cast<float4*>(C)[(size_t)r * 32 + cg] = o;
        }
    }
}

// ---------------- seed: agg = hw * dis (self-loop term folded: (agg+hw*dis)*dis = agg*dis + hw*dis^2) ----

__global__ __launch_bounds__(256) void k_seed(const float* __restrict__ hw,
                                              const float* __restrict__ dis,
                                              float* __restrict__ agg) {
    int i = blockIdx.x * 256 + threadIdx.x;  // float4 units, NN*32 total
    if (i < NN * 32) {
        float d = dis[i >> 5];
        float4 v = reinterpret_cast<const float4*>(hw)[i];
        v.x *= d; v.y *= d; v.z *= d; v.w *= d;
        reinterpret_cast<float4*>(agg)[i] = v;
    }
}

// ---------------- scatter: agg[dst] += hw[src] * dis[src] ----------------

__global__ __launch_bounds__(256) void k_scatter(const float* __restrict__ hw,
                                                 const float* __restrict__ dis,
                                                 const int* __restrict__ src,
                                                 const int* __restrict__ dst,
                                                 float* __restrict__ agg) {
    long long i = (long long)blockIdx.x * 256 + threadIdx.x;  // float4 units, NE*32
    if (i < (long long)NE * 32) {
        int e = (int)(i >> 5), f4 = (int)(i & 31);
        int s = src[e], d = dst[e];
        float ds = dis[s];
        float4 v = reinterpret_cast<const float4*>(hw)[(size_t)s * 32 + f4];
        float* ap = &agg[(size_t)d * 128 + f4 * 4];
        atomicAdd(ap + 0, v.x * ds);
        atomicAdd(ap + 1, v.y * ds);
        atomicAdd(ap + 2, v.z * ds);
        atomicAdd(ap + 3, v.w * ds);
    }
}

// ---------------- combine (in place on agg): h = [relu](agg * dis + b) ----------------

template <bool RELU>
__global__ __launch_bounds__(256) void k_combine(float* __restrict__ agg,
                                                 const float* __restrict__ dis,
                                                 const float* __restrict__ b) {
    int i = blockIdx.x * 256 + threadIdx.x;  // float4 units, NN*32
    if (i < NN * 32) {
        float d = dis[i >> 5];
        float4 bb = reinterpret_cast<const float4*>(b)[i & 31];
        float4 v = reinterpret_cast<float4*>(agg)[i];
        v.x = v.x * d + bb.x;
        v.y = v.y * d + bb.y;
        v.z = v.z * d + bb.z;
        v.w = v.w * d + bb.w;
        if (RELU) {
            v.x = fmaxf(v.x, 0.f); v.y = fmaxf(v.y, 0.f);
            v.z = fmaxf(v.z, 0.f); v.w = fmaxf(v.w, 0.f);
        }
        reinterpret_cast<float4*>(agg)[i] = v;
    }
}

// ---------------- edge MLP: out = relu([h[a],h[b]] @ Wl1 + bl1) @ Wl2 + bl2 ----------------
// 32 edges per block; feat tile (32x256 f32 = 32KB) in LDS; 4x4 register blocking;
// second layer (128->1) via per-thread partial + shfl_xor reduce over the 32 col-groups.

__global__ __launch_bounds__(256) void k_edge_mlp(const float* __restrict__ h,
                                                  const int* __restrict__ eA,
                                                  const int* __restrict__ eB,
                                                  const float* __restrict__ Wl1,
                                                  const float* __restrict__ bl1,
                                                  const float* __restrict__ Wl2,
                                                  const float* __restrict__ bl2,
                                                  float* __restrict__ out) {
    __shared__ float fs[32][256];
    const int t = threadIdx.x;
    const int e0 = blockIdx.x * 32;

    for (int idx = t; idx < 32 * 64; idx += 256) {  // float4 units
        int e = idx >> 6, k4 = idx & 63;
        int node = (k4 < 32) ? eA[e0 + e] : eB[e0 + e];
        float4 v = reinterpret_cast<const float4*>(h)[(size_t)node * 32 + (k4 & 31)];
        reinterpret_cast<float4*>(&fs[e][0])[k4] = v;
    }
    __syncthreads();

    const int cg = t & 31;   // hidden cols cg*4 .. cg*4+3
    const int eg = t >> 5;   // edges eg*4 .. eg*4+3
    float acc[4][4] = {{0.f}};

    const float4* W4 = reinterpret_cast<const float4*>(Wl1);
#pragma unroll 2
    for (int k = 0; k < 256; ++k) {
        float4 w = W4[k * 32 + cg];
        float a0 = fs[eg * 4 + 0][k];
        float a1 = fs[eg * 4 + 1][k];
        float a2 = fs[eg * 4 + 2][k];
        float a3 = fs[eg * 4 + 3][k];
        acc[0][0] += a0 * w.x; acc[0][1] += a0 * w.y; acc[0][2] += a0 * w.z; acc[0][3] += a0 * w.w;
        acc[1][0] += a1 * w.x; acc[1][1] += a1 * w.y; acc[1][2] += a1 * w.z; acc[1][3] += a1 * w.w;
        acc[2][0] += a2 * w.x; acc[2][1] += a2 * w.y; acc[2][2] += a2 * w.z; acc[2][3] += a2 * w.w;
        acc[3][0] += a3 * w.x; acc[3][1] += a3 * w.y; acc[3][2] += a3 * w.z; acc[3][3] += a3 * w.w;
    }

    float4 b1 = reinterpret_cast<const float4*>(bl1)[cg];
    float4 w2 = reinterpret_cast<const float4*>(Wl2)[cg];
    float b2v = bl2[0];

#pragma unroll
    for (int i = 0; i < 4; ++i) {
        float s = fmaxf(acc[i][0] + b1.x, 0.f) * w2.x
                + fmaxf(acc[i][1] + b1.y, 0.f) * w2.y
                + fmaxf(acc[i][2] + b1.z, 0.f) * w2.z
                + fmaxf(acc[i][3] + b1.w, 0.f) * w2.w;
#pragma unroll
        for (int m = 16; m >= 1; m >>= 1) s += __shfl_xor(s, m, 64);
        if (cg == 0) out[e0 + eg * 4 + i] = s + b2v;
    }
}

// ---------------- launch ----------------

extern "C" void kernel_launch(void* const* d_in, const int* in_sizes, int n_in,
                              void* d_out, int out_size, void* d_ws, size_t ws_size,
                              hipStream_t stream) {
    const float* x = (const float*)d_in[0];
    const int* ei = (const int*)d_in[1];
    const int* srcp = ei;
    const int* dstp = ei + NE;

    const int* e_tr_pos = (const int*)d_in[2];
    const int* e_tr_neg = (const int*)d_in[3];
    const int* e_te_pos = (const int*)d_in[4];
    const int* e_te_neg = (const int*)d_in[5];

    const float* W[4] = {(const float*)d_in[6], (const float*)d_in[8],
                         (const float*)d_in[10], (const float*)d_in[12]};
    const float* b[4] = {(const float*)d_in[7], (const float*)d_in[9],
                         (const float*)d_in[11], (const float*)d_in[13]};
    const float* Wl1 = (const float*)d_in[14];
    const float* bl1 = (const float*)d_in[15];
    const float* Wl2 = (const float*)d_in[16];
    const float* bl2 = (const float*)d_in[17];

    float* ws = (float*)d_ws;
    float* dis = ws;                         // 50000 (pad to 50176)
    int* deg = (int*)(ws + 50176);           // 50000 ints (pad to 50176)
    float* B0 = ws + 100352;                 // hw buffer, 6.4M floats
    float* B1 = B0 + 6400000;
    float* B2 = B1 + 6400000;

    k_zero_int<<<(NN + 255) / 256, 256, 0, stream>>>(deg, NN);
    k_count<<<(NE + 255) / 256, 256, 0, stream>>>(dstp, deg);
    k_dis<<<(NN + 255) / 256, 256, 0, stream>>>(deg, dis);

    const int gemm_blocks = (NN + 31) / 32;
    const int vec_blocks = (NN * 32 + 255) / 256;
    const int scat_blocks = (int)(((long long)NE * 32 + 255) / 256);

    float* aggbuf[4] = {B1, B2, B1, B2};
    const float* hin = x;
    for (int l = 0; l < 4; ++l) {
        k_gemm<<<gemm_blocks, 256, 0, stream>>>(hin, W[l], B0, NN);
        k_seed<<<vec_blocks, 256, 0, stream>>>(B0, dis, aggbuf[l]);
        k_scatter<<<scat_blocks, 256, 0, stream>>>(B0, dis, srcp, dstp, aggbuf[l]);
        if (l < 3)
            k_combine<true><<<vec_blocks, 256, 0, stream>>>(aggbuf[l], dis, b[l]);
        else
            k_combine<false><<<vec_blocks, 256, 0, stream>>>(aggbuf[l], dis, b[l]);
        hin = aggbuf[l];
    }

    float* out = (float*)d_out;
    const float* hfin = B2;  // aggbuf[3]
    k_edge_mlp<<<100000 / 32, 256, 0, stream>>>(hfin, e_tr_pos, e_tr_pos + 100000,
                                                Wl1, bl1, Wl2, bl2, out);
    k_edge_mlp<<<100000 / 32, 256, 0, stream>>>(hfin, e_tr_neg, e_tr_neg + 100000,
                                                Wl1, bl1, Wl2, bl2, out + 100000);
    k_edge_mlp<<<20000 / 32, 256, 0, stream>>>(hfin, e_te_pos, e_te_pos + 20000,
                                               Wl1, bl1, Wl2, bl2, out + 200000);
    k_edge_mlp<<<20000 / 32, 256, 0, stream>>>(hfin, e_te_neg, e_te_neg + 20000,
                                               Wl1, bl1, Wl2, bl2, out + 220000);
}

// Round 2
// 1019.254 us; speedup vs baseline: 5.8630x; 5.8630x over previous
//
#include <hip/hip_runtime.h>
#include <math.h>

#define NN 50000
#define NE 800000
#define FD 128

// ---------------- degree / normalization ----------------

__global__ __launch_bounds__(256) void k_zero_int(int* __restrict__ p, int n) {
    int i = blockIdx.x * 256 + threadIdx.x;
    if (i < n) p[i] = 0;
}

__global__ __launch_bounds__(256) void k_count(const int* __restrict__ dst, int* __restrict__ deg) {
    int e = blockIdx.x * 256 + threadIdx.x;
    if (e < NE) atomicAdd(&deg[dst[e]], 1);
}

__global__ __launch_bounds__(256) void k_dis(const int* __restrict__ deg, float* __restrict__ dis) {
    int i = blockIdx.x * 256 + threadIdx.x;
    if (i < NN) dis[i] = (float)(1.0 / sqrt((double)(deg[i] + 1)));
}

// ---------------- exclusive scan over deg -> offs (single block, 256 threads) ----------------

__global__ __launch_bounds__(256) void k_scan(const int* __restrict__ deg, int* __restrict__ offs,
                                              int* __restrict__ cursor) {
    __shared__ int base;
    __shared__ int warp_sums[4];
    const int t = threadIdx.x;
    const int lane = t & 63;
    const int wid = t >> 6;
    if (t == 0) base = 0;
    __syncthreads();
    for (int c = 0; c < NN; c += 256) {
        int i = c + t;
        int v = (i < NN) ? deg[i] : 0;
        int scan = v;
#pragma unroll
        for (int d = 1; d < 64; d <<= 1) {
            int o = __shfl_up(scan, d, 64);
            if (lane >= d) scan += o;
        }
        if (lane == 63) warp_sums[wid] = scan;
        __syncthreads();                       // warp_sums visible; base stable
        int wsum = 0;
        for (int w = 0; w < wid; ++w) wsum += warp_sums[w];
        int excl = base + wsum + scan - v;
        if (i < NN) { offs[i] = excl; cursor[i] = excl; }
        int total_inc = excl + v;
        __syncthreads();                       // all reads of base done
        if (t == 255) base = total_inc;
        __syncthreads();                       // base visible for next iter
    }
    if (t == 0) offs[NN] = base;               // == NE
}

// ---------------- counting-sort fill: srcs_sorted grouped by dst ----------------

__global__ __launch_bounds__(256) void k_fill(const int* __restrict__ src, const int* __restrict__ dst,
                                              int* __restrict__ cursor, int* __restrict__ srcs_sorted) {
    int e = blockIdx.x * 256 + threadIdx.x;
    if (e < NE) {
        int d = dst[e];
        int p = atomicAdd(&cursor[d], 1);
        srcs_sorted[p] = src[e];
    }
}

// ---------------- node GEMM + dis epilogue: C[r] = (A[r] @ W) * dis[r] ----------------
// 32-row tile per block, 256 threads = (8 row-groups x 32 col-groups), 4x4 register block.

__global__ __launch_bounds__(256) void k_gemm(const float* __restrict__ A,
                                              const float* __restrict__ W,
                                              const float* __restrict__ dis,
                                              float* __restrict__ C, int nrows) {
    __shared__ float As[32][128];
    const int t = threadIdx.x;
    const int row0 = blockIdx.x * 32;

    for (int idx = t; idx < 32 * 32; idx += 256) {
        int r = idx >> 5, c = idx & 31;
        float4 v = make_float4(0.f, 0.f, 0.f, 0.f);
        if (row0 + r < nrows)
            v = reinterpret_cast<const float4*>(A)[(size_t)(row0 + r) * 32 + c];
        reinterpret_cast<float4*>(&As[r][0])[c] = v;
    }
    __syncthreads();

    const int cg = t & 31;
    const int eg = t >> 5;
    float acc[4][4] = {{0.f}};

    const float4* W4 = reinterpret_cast<const float4*>(W);
#pragma unroll 4
    for (int k = 0; k < 128; ++k) {
        float4 w = W4[k * 32 + cg];
        float a0 = As[eg * 4 + 0][k];
        float a1 = As[eg * 4 + 1][k];
        float a2 = As[eg * 4 + 2][k];
        float a3 = As[eg * 4 + 3][k];
        acc[0][0] += a0 * w.x; acc[0][1] += a0 * w.y; acc[0][2] += a0 * w.z; acc[0][3] += a0 * w.w;
        acc[1][0] += a1 * w.x; acc[1][1] += a1 * w.y; acc[1][2] += a1 * w.z; acc[1][3] += a1 * w.w;
        acc[2][0] += a2 * w.x; acc[2][1] += a2 * w.y; acc[2][2] += a2 * w.z; acc[2][3] += a2 * w.w;
        acc[3][0] += a3 * w.x; acc[3][1] += a3 * w.y; acc[3][2] += a3 * w.z; acc[3][3] += a3 * w.w;
    }

#pragma unroll
    for (int i = 0; i < 4; ++i) {
        int r = row0 + eg * 4 + i;
        if (r < nrows) {
            float d = dis[r];
            float4 o = make_float4(acc[i][0] * d, acc[i][1] * d, acc[i][2] * d, acc[i][3] * d);
            reinterpret_cast<float4*>(C)[(size_t)r * 32 + cg] = o;
        }
    }
}

// ---------------- gather: h[n] = [relu]( (sum_{e in CSR(n)} hws[src] + hws[n]) * dis[n] + b ) ----

template <bool RELU>
__global__ __launch_bounds__(256) void k_gather(const float* __restrict__ hws,
                                                const float* __restrict__ dis,
                                                const float* __restrict__ b,
                                                const int* __restrict__ offs,
                                                const int* __restrict__ srcs,
                                                float* __restrict__ out) {
    const int t = threadIdx.x;
    const int f4 = t & 31;
    const int node = blockIdx.x * 8 + (t >> 5);
    if (node >= NN) return;

    const float4* H4 = reinterpret_cast<const float4*>(hws);
    float4 acc = H4[(size_t)node * 32 + f4];   // self-loop term (already * dis[node])
    const int e0 = offs[node], e1 = offs[node + 1];
    for (int e = e0; e < e1; ++e) {
        int s = srcs[e];
        float4 v = H4[(size_t)s * 32 + f4];
        acc.x += v.x; acc.y += v.y; acc.z += v.z; acc.w += v.w;
    }
    float d = dis[node];
    float4 bb = reinterpret_cast<const float4*>(b)[f4];
    float4 o;
    o.x = acc.x * d + bb.x;
    o.y = acc.y * d + bb.y;
    o.z = acc.z * d + bb.z;
    o.w = acc.w * d + bb.w;
    if (RELU) {
        o.x = fmaxf(o.x, 0.f); o.y = fmaxf(o.y, 0.f);
        o.z = fmaxf(o.z, 0.f); o.w = fmaxf(o.w, 0.f);
    }
    reinterpret_cast<float4*>(out)[(size_t)node * 32 + f4] = o;
}

// ---------------- edge MLP: out = relu([h[a],h[b]] @ Wl1 + bl1) @ Wl2 + bl2 ----------------

__global__ __launch_bounds__(256) void k_edge_mlp(const float* __restrict__ h,
                                                  const int* __restrict__ eA,
                                                  const int* __restrict__ eB,
                                                  const float* __restrict__ Wl1,
                                                  const float* __restrict__ bl1,
                                                  const float* __restrict__ Wl2,
                                                  const float* __restrict__ bl2,
                                                  float* __restrict__ out) {
    __shared__ float fs[32][256];
    const int t = threadIdx.x;
    const int e0 = blockIdx.x * 32;

    for (int idx = t; idx < 32 * 64; idx += 256) {  // float4 units
        int e = idx >> 6, k4 = idx & 63;
        int node = (k4 < 32) ? eA[e0 + e] : eB[e0 + e];
        float4 v = reinterpret_cast<const float4*>(h)[(size_t)node * 32 + (k4 & 31)];
        reinterpret_cast<float4*>(&fs[e][0])[k4] = v;
    }
    __syncthreads();

    const int cg = t & 31;
    const int eg = t >> 5;
    float acc[4][4] = {{0.f}};

    const float4* W4 = reinterpret_cast<const float4*>(Wl1);
#pragma unroll 2
    for (int k = 0; k < 256; ++k) {
        float4 w = W4[k * 32 + cg];
        float a0 = fs[eg * 4 + 0][k];
        float a1 = fs[eg * 4 + 1][k];
        float a2 = fs[eg * 4 + 2][k];
        float a3 = fs[eg * 4 + 3][k];
        acc[0][0] += a0 * w.x; acc[0][1] += a0 * w.y; acc[0][2] += a0 * w.z; acc[0][3] += a0 * w.w;
        acc[1][0] += a1 * w.x; acc[1][1] += a1 * w.y; acc[1][2] += a1 * w.z; acc[1][3] += a1 * w.w;
        acc[2][0] += a2 * w.x; acc[2][1] += a2 * w.y; acc[2][2] += a2 * w.z; acc[2][3] += a2 * w.w;
        acc[3][0] += a3 * w.x; acc[3][1] += a3 * w.y; acc[3][2] += a3 * w.z; acc[3][3] += a3 * w.w;
    }

    float4 b1 = reinterpret_cast<const float4*>(bl1)[cg];
    float4 w2 = reinterpret_cast<const float4*>(Wl2)[cg];
    float b2v = bl2[0];

#pragma unroll
    for (int i = 0; i < 4; ++i) {
        float s = fmaxf(acc[i][0] + b1.x, 0.f) * w2.x
                + fmaxf(acc[i][1] + b1.y, 0.f) * w2.y
                + fmaxf(acc[i][2] + b1.z, 0.f) * w2.z
                + fmaxf(acc[i][3] + b1.w, 0.f) * w2.w;
#pragma unroll
        for (int m = 16; m >= 1; m >>= 1) s += __shfl_xor(s, m, 64);
        if (cg == 0) out[e0 + eg * 4 + i] = s + b2v;
    }
}

// ---------------- launch ----------------

extern "C" void kernel_launch(void* const* d_in, const int* in_sizes, int n_in,
                              void* d_out, int out_size, void* d_ws, size_t ws_size,
                              hipStream_t stream) {
    const float* x = (const float*)d_in[0];
    const int* ei = (const int*)d_in[1];
    const int* srcp = ei;
    const int* dstp = ei + NE;

    const int* e_tr_pos = (const int*)d_in[2];
    const int* e_tr_neg = (const int*)d_in[3];
    const int* e_te_pos = (const int*)d_in[4];
    const int* e_te_neg = (const int*)d_in[5];

    const float* W[4] = {(const float*)d_in[6], (const float*)d_in[8],
                         (const float*)d_in[10], (const float*)d_in[12]};
    const float* b[4] = {(const float*)d_in[7], (const float*)d_in[9],
                         (const float*)d_in[11], (const float*)d_in[13]};
    const float* Wl1 = (const float*)d_in[14];
    const float* bl1 = (const float*)d_in[15];
    const float* Wl2 = (const float*)d_in[16];
    const float* bl2 = (const float*)d_in[17];

    float* ws = (float*)d_ws;
    float* dis = ws;                          // [0, 50176)
    int* deg = (int*)(ws + 50176);            // [50176, 100352)
    int* offs = (int*)(ws + 100352);          // 50177 ints -> [100352, 150529)
    int* cursor = (int*)(ws + 150532);        // [150532, 200708)
    int* srcs = (int*)(ws + 200708);          // 800000 ints -> [200708, 1000708)
    float* B0 = ws + 1000708;                 // hws, 6.4M floats
    float* B1 = B0 + 6400000;
    float* B2 = B1 + 6400000;

    k_zero_int<<<(NN + 255) / 256, 256, 0, stream>>>(deg, NN);
    k_count<<<(NE + 255) / 256, 256, 0, stream>>>(dstp, deg);
    k_dis<<<(NN + 255) / 256, 256, 0, stream>>>(deg, dis);
    k_scan<<<1, 256, 0, stream>>>(deg, offs, cursor);
    k_fill<<<(NE + 255) / 256, 256, 0, stream>>>(srcp, dstp, cursor, srcs);

    const int gemm_blocks = (NN + 31) / 32;
    const int gath_blocks = (NN + 7) / 8;

    // ping-pong: x->B1->B2->B1->B2 ; hws always in B0
    float* hout[4] = {B1, B2, B1, B2};
    const float* hin = x;
    for (int l = 0; l < 4; ++l) {
        k_gemm<<<gemm_blocks, 256, 0, stream>>>(hin, W[l], dis, B0, NN);
        if (l < 3)
            k_gather<true><<<gath_blocks, 256, 0, stream>>>(B0, dis, b[l], offs, srcs, hout[l]);
        else
            k_gather<false><<<gath_blocks, 256, 0, stream>>>(B0, dis, b[l], offs, srcs, hout[l]);
        hin = hout[l];
    }

    float* out = (float*)d_out;
    const float* hfin = B2;  // hout[3]
    k_edge_mlp<<<100000 / 32, 256, 0, stream>>>(hfin, e_tr_pos, e_tr_pos + 100000,
                                                Wl1, bl1, Wl2, bl2, out);
    k_edge_mlp<<<100000 / 32, 256, 0, stream>>>(hfin, e_tr_neg, e_tr_neg + 100000,
                                                Wl1, bl1, Wl2, bl2, out + 100000);
    k_edge_mlp<<<20000 / 32, 256, 0, stream>>>(hfin, e_te_pos, e_te_pos + 20000,
                                               Wl1, bl1, Wl2, bl2, out + 200000);
    k_edge_mlp<<<20000 / 32, 256, 0, stream>>>(hfin, e_te_neg, e_te_neg + 20000,
                                               Wl1, bl1, Wl2, bl2, out + 220000);
}

// Round 3
// 784.935 us; speedup vs baseline: 7.6132x; 1.2985x over previous
//
#include <hip/hip_runtime.h>
#include <math.h>

#define NN 50000
#define NE 800000
#define FD 128

// ---------------- degree / normalization ----------------

__global__ __launch_bounds__(256) void k_zero_int(int* __restrict__ p, int n) {
    int i = blockIdx.x * 256 + threadIdx.x;
    if (i < n) p[i] = 0;
}

__global__ __launch_bounds__(256) void k_count(const int* __restrict__ dst, int* __restrict__ deg) {
    int e = blockIdx.x * 256 + threadIdx.x;
    if (e < NE) atomicAdd(&deg[dst[e]], 1);
}

__global__ __launch_bounds__(256) void k_dis(const int* __restrict__ deg, float* __restrict__ dis) {
    int i = blockIdx.x * 256 + threadIdx.x;
    if (i < NN) dis[i] = (float)(1.0 / sqrt((double)(deg[i] + 1)));
}

// ---------------- exclusive scan over deg -> offs (single block, 256 threads) ----------------

__global__ __launch_bounds__(256) void k_scan(const int* __restrict__ deg, int* __restrict__ offs,
                                              int* __restrict__ cursor) {
    __shared__ int base;
    __shared__ int warp_sums[4];
    const int t = threadIdx.x;
    const int lane = t & 63;
    const int wid = t >> 6;
    if (t == 0) base = 0;
    __syncthreads();
    for (int c = 0; c < NN; c += 256) {
        int i = c + t;
        int v = (i < NN) ? deg[i] : 0;
        int scan = v;
#pragma unroll
        for (int d = 1; d < 64; d <<= 1) {
            int o = __shfl_up(scan, d, 64);
            if (lane >= d) scan += o;
        }
        if (lane == 63) warp_sums[wid] = scan;
        __syncthreads();
        int wsum = 0;
        for (int w = 0; w < wid; ++w) wsum += warp_sums[w];
        int excl = base + wsum + scan - v;
        if (i < NN) { offs[i] = excl; cursor[i] = excl; }
        int total_inc = excl + v;
        __syncthreads();
        if (t == 255) base = total_inc;
        __syncthreads();
    }
    if (t == 0) offs[NN] = base;               // == NE
}

// ---------------- counting-sort fill: srcs_sorted grouped by dst ----------------

__global__ __launch_bounds__(256) void k_fill(const int* __restrict__ src, const int* __restrict__ dst,
                                              int* __restrict__ cursor, int* __restrict__ srcs_sorted) {
    int e = blockIdx.x * 256 + threadIdx.x;
    if (e < NE) {
        int d = dst[e];
        int p = atomicAdd(&cursor[d], 1);
        srcs_sorted[p] = src[e];
    }
}

// ---------------- node GEMM: C[r] = (A[r] @ W) [* dis[r] if SCALE] ----------------
// 32-row tile, 256 threads = 8 row-groups x 32 col-groups, 4x4 register block,
// k-unrolled by 4 with float4 LDS broadcasts for A.

template <bool SCALE>
__global__ __launch_bounds__(256) void k_gemm(const float* __restrict__ A,
                                              const float* __restrict__ W,
                                              const float* __restrict__ dis,
                                              float* __restrict__ C, int nrows) {
    __shared__ float As[32][128];
    const int t = threadIdx.x;
    const int row0 = blockIdx.x * 32;

    for (int idx = t; idx < 32 * 32; idx += 256) {
        int r = idx >> 5, c = idx & 31;
        float4 v = make_float4(0.f, 0.f, 0.f, 0.f);
        if (row0 + r < nrows)
            v = reinterpret_cast<const float4*>(A)[(size_t)(row0 + r) * 32 + c];
        reinterpret_cast<float4*>(&As[r][0])[c] = v;
    }
    __syncthreads();

    const int cg = t & 31;
    const int eg = t >> 5;
    float acc[4][4] = {{0.f}};

    const float4* W4 = reinterpret_cast<const float4*>(W);
    const float4* A0 = reinterpret_cast<const float4*>(&As[eg * 4 + 0][0]);
    const float4* A1 = reinterpret_cast<const float4*>(&As[eg * 4 + 1][0]);
    const float4* A2 = reinterpret_cast<const float4*>(&As[eg * 4 + 2][0]);
    const float4* A3 = reinterpret_cast<const float4*>(&As[eg * 4 + 3][0]);

#pragma unroll 2
    for (int k4 = 0; k4 < 32; ++k4) {
        float4 w0 = W4[(k4 * 4 + 0) * 32 + cg];
        float4 w1 = W4[(k4 * 4 + 1) * 32 + cg];
        float4 w2 = W4[(k4 * 4 + 2) * 32 + cg];
        float4 w3 = W4[(k4 * 4 + 3) * 32 + cg];
        float4 a0 = A0[k4], a1 = A1[k4], a2 = A2[k4], a3 = A3[k4];

#define ROWFMA(i, ai)                                                          \
        acc[i][0] += ai.x * w0.x + ai.y * w1.x + ai.z * w2.x + ai.w * w3.x;    \
        acc[i][1] += ai.x * w0.y + ai.y * w1.y + ai.z * w2.y + ai.w * w3.y;    \
        acc[i][2] += ai.x * w0.z + ai.y * w1.z + ai.z * w2.z + ai.w * w3.z;    \
        acc[i][3] += ai.x * w0.w + ai.y * w1.w + ai.z * w2.w + ai.w * w3.w;
        ROWFMA(0, a0) ROWFMA(1, a1) ROWFMA(2, a2) ROWFMA(3, a3)
#undef ROWFMA
    }

#pragma unroll
    for (int i = 0; i < 4; ++i) {
        int r = row0 + eg * 4 + i;
        if (r < nrows) {
            float d = SCALE ? dis[r] : 1.0f;
            float4 o = make_float4(acc[i][0] * d, acc[i][1] * d, acc[i][2] * d, acc[i][3] * d);
            reinterpret_cast<float4*>(C)[(size_t)r * 32 + cg] = o;
        }
    }
}

// ---------------- gather: h[n] = [relu]( (sum_{e in CSR(n)} hws[src] + hws[n]) * dis[n] + b ) ----

template <bool RELU>
__global__ __launch_bounds__(256) void k_gather(const float* __restrict__ hws,
                                                const float* __restrict__ dis,
                                                const float* __restrict__ b,
                                                const int* __restrict__ offs,
                                                const int* __restrict__ srcs,
                                                float* __restrict__ out) {
    const int t = threadIdx.x;
    const int f4 = t & 31;
    const int node = blockIdx.x * 8 + (t >> 5);
    if (node >= NN) return;

    const float4* H4 = reinterpret_cast<const float4*>(hws);
    float4 acc = H4[(size_t)node * 32 + f4];   // self-loop term (already * dis[node])
    const int e0 = offs[node], e1 = offs[node + 1];
    int e = e0;
    for (; e + 4 <= e1; e += 4) {
        int s0 = srcs[e + 0], s1 = srcs[e + 1], s2 = srcs[e + 2], s3 = srcs[e + 3];
        float4 v0 = H4[(size_t)s0 * 32 + f4];
        float4 v1 = H4[(size_t)s1 * 32 + f4];
        float4 v2 = H4[(size_t)s2 * 32 + f4];
        float4 v3 = H4[(size_t)s3 * 32 + f4];
        acc.x += v0.x + v1.x + v2.x + v3.x;
        acc.y += v0.y + v1.y + v2.y + v3.y;
        acc.z += v0.z + v1.z + v2.z + v3.z;
        acc.w += v0.w + v1.w + v2.w + v3.w;
    }
    for (; e < e1; ++e) {
        int s = srcs[e];
        float4 v = H4[(size_t)s * 32 + f4];
        acc.x += v.x; acc.y += v.y; acc.z += v.z; acc.w += v.w;
    }
    float d = dis[node];
    float4 bb = reinterpret_cast<const float4*>(b)[f4];
    float4 o;
    o.x = acc.x * d + bb.x;
    o.y = acc.y * d + bb.y;
    o.z = acc.z * d + bb.z;
    o.w = acc.w * d + bb.w;
    if (RELU) {
        o.x = fmaxf(o.x, 0.f); o.y = fmaxf(o.y, 0.f);
        o.z = fmaxf(o.z, 0.f); o.w = fmaxf(o.w, 0.f);
    }
    reinterpret_cast<float4*>(out)[(size_t)node * 32 + f4] = o;
}

// ---------------- edge score: out[e] = relu(U[a] + V[b] + bl1) . Wl2 + bl2 ----------------
// 8 edges/block, 32 lanes per edge (float4 each), shfl_xor reduce within the 32-lane group.

__global__ __launch_bounds__(256) void k_edge_score(const float* __restrict__ U,
                                                    const float* __restrict__ V,
                                                    const int* __restrict__ eA,
                                                    const int* __restrict__ eB,
                                                    const float* __restrict__ bl1,
                                                    const float* __restrict__ Wl2,
                                                    const float* __restrict__ bl2,
                                                    float* __restrict__ out, int nedges) {
    const int t = threadIdx.x;
    const int f4 = t & 31;
    const int e = blockIdx.x * 8 + (t >> 5);
    if (e >= nedges) return;

    int a = eA[e], bn = eB[e];
    float4 u = reinterpret_cast<const float4*>(U)[(size_t)a * 32 + f4];
    float4 v = reinterpret_cast<const float4*>(V)[(size_t)bn * 32 + f4];
    float4 bb = reinterpret_cast<const float4*>(bl1)[f4];
    float4 w2 = reinterpret_cast<const float4*>(Wl2)[f4];

    float s = fmaxf(u.x + v.x + bb.x, 0.f) * w2.x
            + fmaxf(u.y + v.y + bb.y, 0.f) * w2.y
            + fmaxf(u.z + v.z + bb.z, 0.f) * w2.z
            + fmaxf(u.w + v.w + bb.w, 0.f) * w2.w;
#pragma unroll
    for (int m = 16; m >= 1; m >>= 1) s += __shfl_xor(s, m, 64);
    if (f4 == 0) out[e] = s + bl2[0];
}

// ---------------- launch ----------------

extern "C" void kernel_launch(void* const* d_in, const int* in_sizes, int n_in,
                              void* d_out, int out_size, void* d_ws, size_t ws_size,
                              hipStream_t stream) {
    const float* x = (const float*)d_in[0];
    const int* ei = (const int*)d_in[1];
    const int* srcp = ei;
    const int* dstp = ei + NE;

    const int* e_tr_pos = (const int*)d_in[2];
    const int* e_tr_neg = (const int*)d_in[3];
    const int* e_te_pos = (const int*)d_in[4];
    const int* e_te_neg = (const int*)d_in[5];

    const float* W[4] = {(const float*)d_in[6], (const float*)d_in[8],
                         (const float*)d_in[10], (const float*)d_in[12]};
    const float* b[4] = {(const float*)d_in[7], (const float*)d_in[9],
                         (const float*)d_in[11], (const float*)d_in[13]};
    const float* Wl1 = (const float*)d_in[14];
    const float* bl1 = (const float*)d_in[15];
    const float* Wl2 = (const float*)d_in[16];
    const float* bl2 = (const float*)d_in[17];

    float* ws = (float*)d_ws;
    float* dis = ws;                          // [0, 50176)
    int* deg = (int*)(ws + 50176);            // [50176, 100352)
    int* offs = (int*)(ws + 100352);          // 50177 ints
    int* cursor = (int*)(ws + 150532);
    int* srcs = (int*)(ws + 200708);          // 800000 ints
    float* B0 = ws + 1000708;                 // hws scratch / later U
    float* B1 = B0 + 6400000;                 // h1,h3 / later V
    float* B2 = B1 + 6400000;                 // h2,h4(final)

    k_zero_int<<<(NN + 255) / 256, 256, 0, stream>>>(deg, NN);
    k_count<<<(NE + 255) / 256, 256, 0, stream>>>(dstp, deg);
    k_dis<<<(NN + 255) / 256, 256, 0, stream>>>(deg, dis);
    k_scan<<<1, 256, 0, stream>>>(deg, offs, cursor);
    k_fill<<<(NE + 255) / 256, 256, 0, stream>>>(srcp, dstp, cursor, srcs);

    const int gemm_blocks = (NN + 31) / 32;
    const int gath_blocks = (NN + 7) / 8;

    // ping-pong: x->B1->B2->B1->B2 ; hws always in B0
    float* hout[4] = {B1, B2, B1, B2};
    const float* hin = x;
    for (int l = 0; l < 4; ++l) {
        k_gemm<true><<<gemm_blocks, 256, 0, stream>>>(hin, W[l], dis, B0, NN);
        if (l < 3)
            k_gather<true><<<gath_blocks, 256, 0, stream>>>(B0, dis, b[l], offs, srcs, hout[l]);
        else
            k_gather<false><<<gath_blocks, 256, 0, stream>>>(B0, dis, b[l], offs, srcs, hout[l]);
        hin = hout[l];
    }

    const float* hfin = B2;  // final embeddings
    float* Ubuf = B0;        // free now
    float* Vbuf = B1;        // free now
    k_gemm<false><<<gemm_blocks, 256, 0, stream>>>(hfin, Wl1, dis, Ubuf, NN);
    k_gemm<false><<<gemm_blocks, 256, 0, stream>>>(hfin, Wl1 + 128 * 128, dis, Vbuf, NN);

    float* out = (float*)d_out;
    k_edge_score<<<(100000 + 7) / 8, 256, 0, stream>>>(Ubuf, Vbuf, e_tr_pos, e_tr_pos + 100000,
                                                       bl1, Wl2, bl2, out, 100000);
    k_edge_score<<<(100000 + 7) / 8, 256, 0, stream>>>(Ubuf, Vbuf, e_tr_neg, e_tr_neg + 100000,
                                                       bl1, Wl2, bl2, out + 100000, 100000);
    k_edge_score<<<(20000 + 7) / 8, 256, 0, stream>>>(Ubuf, Vbuf, e_te_pos, e_te_pos + 20000,
                                                      bl1, Wl2, bl2, out + 200000, 20000);
    k_edge_score<<<(20000 + 7) / 8, 256, 0, stream>>>(Ubuf, Vbuf, e_te_neg, e_te_neg + 20000,
                                                      bl1, Wl2, bl2, out + 220000, 20000);
}

// Round 4
// 569.610 us; speedup vs baseline: 10.4912x; 1.3780x over previous
//
#include <hip/hip_runtime.h>
#include <math.h>

#define NN 50000
#define NE 800000
#define FD 128
#define SCAN_B 196   // ceil(50176/256)

// ---------------- degree ----------------

__global__ __launch_bounds__(256) void k_zero_int(int* __restrict__ p, int n) {
    int i = blockIdx.x * 256 + threadIdx.x;
    if (i < n) p[i] = 0;
}

__global__ __launch_bounds__(256) void k_count(const int* __restrict__ dst, int* __restrict__ deg) {
    int e = blockIdx.x * 256 + threadIdx.x;
    if (e < NE) atomicAdd(&deg[dst[e]], 1);
}

// ---------------- parallel exclusive scan of deg (50000) ----------------
// scan1: per-block (256 elems) exclusive scan -> partial, block total -> bsum; also dis.

__global__ __launch_bounds__(256) void k_scan1(const int* __restrict__ deg,
                                               int* __restrict__ partial,
                                               int* __restrict__ bsum,
                                               float* __restrict__ dis) {
    __shared__ int wsum[4];
    const int t = threadIdx.x, lane = t & 63, wid = t >> 6;
    const int i = blockIdx.x * 256 + t;
    int v = (i < NN) ? deg[i] : 0;
    int sc = v;
#pragma unroll
    for (int d = 1; d < 64; d <<= 1) {
        int o = __shfl_up(sc, d, 64);
        if (lane >= d) sc += o;
    }
    if (lane == 63) wsum[wid] = sc;
    __syncthreads();
    int pre = 0;
    for (int w = 0; w < wid; ++w) pre += wsum[w];
    if (i < NN) {
        partial[i] = pre + sc - v;
        dis[i] = (float)(1.0 / sqrt((double)(v + 1)));
    }
    if (t == 255) bsum[blockIdx.x] = pre + sc;
}

// scan2: single block scans SCAN_B block sums to exclusive (in place; each thread rw its own slot).

__global__ __launch_bounds__(256) void k_scan2(int* __restrict__ bsum) {
    __shared__ int wsum[4];
    const int t = threadIdx.x, lane = t & 63, wid = t >> 6;
    int v = (t < SCAN_B) ? bsum[t] : 0;
    int sc = v;
#pragma unroll
    for (int d = 1; d < 64; d <<= 1) {
        int o = __shfl_up(sc, d, 64);
        if (lane >= d) sc += o;
    }
    if (lane == 63) wsum[wid] = sc;
    __syncthreads();
    int pre = 0;
    for (int w = 0; w < wid; ++w) pre += wsum[w];
    if (t < SCAN_B) bsum[t] = pre + sc - v;
}

// scan3: offs/cursor = partial + bsum[block]

__global__ __launch_bounds__(256) void k_scan3(const int* __restrict__ partial,
                                               const int* __restrict__ bsum,
                                               int* __restrict__ offs,
                                               int* __restrict__ cursor) {
    const int i = blockIdx.x * 256 + threadIdx.x;
    if (i < NN) {
        int o = partial[i] + bsum[blockIdx.x];
        offs[i] = o;
        cursor[i] = o;
    }
    if (i == 0) offs[NN] = NE;
}

// ---------------- counting-sort fill: srcs grouped by dst ----------------

__global__ __launch_bounds__(256) void k_fill(const int* __restrict__ src, const int* __restrict__ dst,
                                              int* __restrict__ cursor, int* __restrict__ srcs_sorted) {
    int e = blockIdx.x * 256 + threadIdx.x;
    if (e < NE) {
        int d = dst[e];
        int p = atomicAdd(&cursor[d], 1);
        srcs_sorted[p] = src[e];
    }
}

// ---------------- node GEMM: C[r] = (A[r] @ W) [* dis[r] if SCALE] ----------------
// 64-row tile, 256 threads = 8 groups x 8 rows, 32 col-groups; 8x4 register block;
// k-unrolled by 4 with float4 LDS broadcasts.

template <bool SCALE>
__global__ __launch_bounds__(256) void k_gemm(const float* __restrict__ A,
                                              const float* __restrict__ W,
                                              const float* __restrict__ dis,
                                              float* __restrict__ C, int nrows) {
    __shared__ float As[64][128];
    const int t = threadIdx.x;
    const int row0 = blockIdx.x * 64;

    for (int idx = t; idx < 64 * 32; idx += 256) {
        int r = idx >> 5, c = idx & 31;
        float4 v = make_float4(0.f, 0.f, 0.f, 0.f);
        if (row0 + r < nrows)
            v = reinterpret_cast<const float4*>(A)[(size_t)(row0 + r) * 32 + c];
        reinterpret_cast<float4*>(&As[r][0])[c] = v;
    }
    __syncthreads();

    const int cg = t & 31;
    const int eg = t >> 5;           // rows eg*8 .. eg*8+7
    float acc[8][4] = {{0.f}};

    const float4* W4 = reinterpret_cast<const float4*>(W);
    const float4* As4 = reinterpret_cast<const float4*>(As);

    for (int k4 = 0; k4 < 32; ++k4) {
        float4 w0 = W4[(k4 * 4 + 0) * 32 + cg];
        float4 w1 = W4[(k4 * 4 + 1) * 32 + cg];
        float4 w2 = W4[(k4 * 4 + 2) * 32 + cg];
        float4 w3 = W4[(k4 * 4 + 3) * 32 + cg];
#pragma unroll
        for (int i = 0; i < 8; ++i) {
            float4 a = As4[(eg * 8 + i) * 32 + k4];
            acc[i][0] += a.x * w0.x + a.y * w1.x + a.z * w2.x + a.w * w3.x;
            acc[i][1] += a.x * w0.y + a.y * w1.y + a.z * w2.y + a.w * w3.y;
            acc[i][2] += a.x * w0.z + a.y * w1.z + a.z * w2.z + a.w * w3.z;
            acc[i][3] += a.x * w0.w + a.y * w1.w + a.z * w2.w + a.w * w3.w;
        }
    }

#pragma unroll
    for (int i = 0; i < 8; ++i) {
        int r = row0 + eg * 8 + i;
        if (r < nrows) {
            float d = SCALE ? dis[r] : 1.0f;
            float4 o = make_float4(acc[i][0] * d, acc[i][1] * d, acc[i][2] * d, acc[i][3] * d);
            reinterpret_cast<float4*>(C)[(size_t)r * 32 + cg] = o;
        }
    }
}

// ---------------- gather: h[n] = [relu]( (sum_{CSR(n)} hws[src] + hws[n]) * dis[n] + b ) ----

template <bool RELU>
__global__ __launch_bounds__(256) void k_gather(const float* __restrict__ hws,
                                                const float* __restrict__ dis,
                                                const float* __restrict__ b,
                                                const int* __restrict__ offs,
                                                const int* __restrict__ srcs,
                                                float* __restrict__ out) {
    const int t = threadIdx.x;
    const int f4 = t & 31;
    const int node = blockIdx.x * 8 + (t >> 5);
    if (node >= NN) return;

    const float4* H4 = reinterpret_cast<const float4*>(hws);
    float4 acc = H4[(size_t)node * 32 + f4];   // self-loop (already * dis[node])
    const int e0 = offs[node], e1 = offs[node + 1];
    int e = e0;
    for (; e + 4 <= e1; e += 4) {
        int s0 = srcs[e + 0], s1 = srcs[e + 1], s2 = srcs[e + 2], s3 = srcs[e + 3];
        float4 v0 = H4[(size_t)s0 * 32 + f4];
        float4 v1 = H4[(size_t)s1 * 32 + f4];
        float4 v2 = H4[(size_t)s2 * 32 + f4];
        float4 v3 = H4[(size_t)s3 * 32 + f4];
        acc.x += v0.x + v1.x + v2.x + v3.x;
        acc.y += v0.y + v1.y + v2.y + v3.y;
        acc.z += v0.z + v1.z + v2.z + v3.z;
        acc.w += v0.w + v1.w + v2.w + v3.w;
    }
    for (; e < e1; ++e) {
        int s = srcs[e];
        float4 v = H4[(size_t)s * 32 + f4];
        acc.x += v.x; acc.y += v.y; acc.z += v.z; acc.w += v.w;
    }
    float d = dis[node];
    float4 bb = reinterpret_cast<const float4*>(b)[f4];
    float4 o;
    o.x = acc.x * d + bb.x;
    o.y = acc.y * d + bb.y;
    o.z = acc.z * d + bb.z;
    o.w = acc.w * d + bb.w;
    if (RELU) {
        o.x = fmaxf(o.x, 0.f); o.y = fmaxf(o.y, 0.f);
        o.z = fmaxf(o.z, 0.f); o.w = fmaxf(o.w, 0.f);
    }
    reinterpret_cast<float4*>(out)[(size_t)node * 32 + f4] = o;
}

// ---------------- edge score: out[e] = relu(U[a] + V[b] + bl1) . Wl2 + bl2 ----------------

__global__ __launch_bounds__(256) void k_edge_score(const float* __restrict__ U,
                                                    const float* __restrict__ V,
                                                    const int* __restrict__ eA,
                                                    const int* __restrict__ eB,
                                                    const float* __restrict__ bl1,
                                                    const float* __restrict__ Wl2,
                                                    const float* __restrict__ bl2,
                                                    float* __restrict__ out, int nedges) {
    const int t = threadIdx.x;
    const int f4 = t & 31;
    const int e = blockIdx.x * 8 + (t >> 5);
    if (e >= nedges) return;

    int a = eA[e], bn = eB[e];
    float4 u = reinterpret_cast<const float4*>(U)[(size_t)a * 32 + f4];
    float4 v = reinterpret_cast<const float4*>(V)[(size_t)bn * 32 + f4];
    float4 bb = reinterpret_cast<const float4*>(bl1)[f4];
    float4 w2 = reinterpret_cast<const float4*>(Wl2)[f4];

    float s = fmaxf(u.x + v.x + bb.x, 0.f) * w2.x
            + fmaxf(u.y + v.y + bb.y, 0.f) * w2.y
            + fmaxf(u.z + v.z + bb.z, 0.f) * w2.z
            + fmaxf(u.w + v.w + bb.w, 0.f) * w2.w;
#pragma unroll
    for (int m = 16; m >= 1; m >>= 1) s += __shfl_xor(s, m, 64);
    if (f4 == 0) out[e] = s + bl2[0];
}

// ---------------- launch ----------------

extern "C" void kernel_launch(void* const* d_in, const int* in_sizes, int n_in,
                              void* d_out, int out_size, void* d_ws, size_t ws_size,
                              hipStream_t stream) {
    const float* x = (const float*)d_in[0];
    const int* ei = (const int*)d_in[1];
    const int* srcp = ei;
    const int* dstp = ei + NE;

    const int* e_tr_pos = (const int*)d_in[2];
    const int* e_tr_neg = (const int*)d_in[3];
    const int* e_te_pos = (const int*)d_in[4];
    const int* e_te_neg = (const int*)d_in[5];

    const float* W[4] = {(const float*)d_in[6], (const float*)d_in[8],
                         (const float*)d_in[10], (const float*)d_in[12]};
    const float* b[4] = {(const float*)d_in[7], (const float*)d_in[9],
                         (const float*)d_in[11], (const float*)d_in[13]};
    const float* Wl1 = (const float*)d_in[14];
    const float* bl1 = (const float*)d_in[15];
    const float* Wl2 = (const float*)d_in[16];
    const float* bl2 = (const float*)d_in[17];

    float* ws = (float*)d_ws;
    float* dis = ws;                          // [0, 50176)
    int* deg = (int*)(ws + 50176);            // [50176, 100352)
    int* offs = (int*)(ws + 100352);          // 50001 ints, region to 150784
    int* cursor = (int*)(ws + 150784);        // 50176 -> 200960
    int* bsum = (int*)(ws + 200960);          // 256   -> 201216
    int* srcs = (int*)(ws + 201216);          // 800000 -> 1001216
    float* B0 = ws + 1001216;                 // hws / U
    float* B1 = B0 + 6400000;                 // h1,h3 / V
    float* B2 = B1 + 6400000;                 // h2,h4(final); start doubles as scan scratch
    int* partial = (int*)B2;                  // dead until layer-2 gather

    k_zero_int<<<(NN + 255) / 256, 256, 0, stream>>>(deg, NN);
    k_count<<<(NE + 255) / 256, 256, 0, stream>>>(dstp, deg);
    k_scan1<<<SCAN_B, 256, 0, stream>>>(deg, partial, bsum, dis);
    k_scan2<<<1, 256, 0, stream>>>(bsum);
    k_scan3<<<SCAN_B, 256, 0, stream>>>(partial, bsum, offs, cursor);
    k_fill<<<(NE + 255) / 256, 256, 0, stream>>>(srcp, dstp, cursor, srcs);

    const int gemm_blocks = (NN + 63) / 64;
    const int gath_blocks = (NN + 7) / 8;

    float* hout[4] = {B1, B2, B1, B2};
    const float* hin = x;
    for (int l = 0; l < 4; ++l) {
        k_gemm<true><<<gemm_blocks, 256, 0, stream>>>(hin, W[l], dis, B0, NN);
        if (l < 3)
            k_gather<true><<<gath_blocks, 256, 0, stream>>>(B0, dis, b[l], offs, srcs, hout[l]);
        else
            k_gather<false><<<gath_blocks, 256, 0, stream>>>(B0, dis, b[l], offs, srcs, hout[l]);
        hin = hout[l];
    }

    const float* hfin = B2;  // final embeddings
    float* Ubuf = B0;
    float* Vbuf = B1;
    k_gemm<false><<<gemm_blocks, 256, 0, stream>>>(hfin, Wl1, dis, Ubuf, NN);
    k_gemm<false><<<gemm_blocks, 256, 0, stream>>>(hfin, Wl1 + 128 * 128, dis, Vbuf, NN);

    float* out = (float*)d_out;
    k_edge_score<<<(100000 + 7) / 8, 256, 0, stream>>>(Ubuf, Vbuf, e_tr_pos, e_tr_pos + 100000,
                                                       bl1, Wl2, bl2, out, 100000);
    k_edge_score<<<(100000 + 7) / 8, 256, 0, stream>>>(Ubuf, Vbuf, e_tr_neg, e_tr_neg + 100000,
                                                       bl1, Wl2, bl2, out + 100000, 100000);
    k_edge_score<<<(20000 + 7) / 8, 256, 0, stream>>>(Ubuf, Vbuf, e_te_pos, e_te_pos + 20000,
                                                      bl1, Wl2, bl2, out + 200000, 20000);
    k_edge_score<<<(20000 + 7) / 8, 256, 0, stream>>>(Ubuf, Vbuf, e_te_neg, e_te_neg + 20000,
                                                      bl1, Wl2, bl2, out + 220000, 20000);
}